// Round 8
// baseline (627.099 us; speedup 1.0000x reference)
//
#include <hip/hip_runtime.h>
#include <hip/hip_fp16.h>
#include <stdint.h>

typedef int i32x4 __attribute__((ext_vector_type(4)));

#define IN_F  4096
#define OUT_F 11008
#define MROWS 8192
#define RTILES 64          // MROWS/128
#define CTILES 86          // OUT_F/128
#define TILE_BYTES (128 * IN_F)   // 524288 B of int8 per 128-row tile

// ---------------- Pre-pass 1: smooth + fake-quant activations to int8 ----------------
// x, pqs are float32 on device (fp16-valued; harness promotes fp16 -> f32).
// xs = fp16(x * pqs)  [product of two fp16-valued f32 is exact in f32, so
//                      __float2half reproduces the reference's fp16 Mul]
// q  = clip(rne(f32(xs) / s), -128, 127)
__global__ __launch_bounds__(256) void quant_act_kernel(
    const float* __restrict__ x,        // group base: [nrows][4096]
    const float* __restrict__ pqs,
    const float* __restrict__ iscale,
    int8_t* __restrict__ q)
{
    const int i = blockIdx.x * blockDim.x + threadIdx.x;   // one thread per 8 elements
    const float s = iscale[0];
    const size_t base = (size_t)i * 8;
    const int col = (int)(base & (IN_F - 1));              // row length divides 8-groups

    const float4 x0 = *(const float4*)(x + base);
    const float4 x1 = *(const float4*)(x + base + 4);
    const float4 p0 = *(const float4*)(pqs + col);
    const float4 p1 = *(const float4*)(pqs + col + 4);

    float xs[8];
    xs[0] = x0.x * p0.x; xs[1] = x0.y * p0.y; xs[2] = x0.z * p0.z; xs[3] = x0.w * p0.w;
    xs[4] = x1.x * p1.x; xs[5] = x1.y * p1.y; xs[6] = x1.z * p1.z; xs[7] = x1.w * p1.w;

    unsigned int lo = 0, hi = 0;
    #pragma unroll
    for (int j = 0; j < 8; ++j) {
        float xm = __half2float(__float2half(xs[j]));      // fp16 Mul materialization
        float qf = nearbyintf(xm / s);                     // f32 div + RNE (np.round)
        qf = fminf(fmaxf(qf, -128.0f), 127.0f);
        int qi = (int)qf;
        unsigned int b = (unsigned int)(qi & 0xff);
        if (j < 4) lo |= b << (8 * j);
        else       hi |= b << (8 * (j - 4));
    }
    *(uint2*)(q + base) = make_uint2(lo, hi);
}

// ---------------- Pre-pass 2: pack int32-stored int8 weights ----------------
__global__ __launch_bounds__(256) void pack_w_kernel(
    const int* __restrict__ w, int8_t* __restrict__ wq)
{
    const size_t i = (size_t)(blockIdx.x * blockDim.x + threadIdx.x) * 8;
    const int4 a = *(const int4*)(w + i);
    const int4 b = *(const int4*)(w + i + 4);
    unsigned int lo = (a.x & 0xff) | ((a.y & 0xff) << 8) | ((a.z & 0xff) << 16) | ((unsigned int)(a.w & 0xff) << 24);
    unsigned int hi = (b.x & 0xff) | ((b.y & 0xff) << 8) | ((b.z & 0xff) << 16) | ((unsigned int)(b.w & 0xff) << 24);
    *(uint2*)(wq + i) = make_uint2(lo, hi);
}

// ---------------- int8 GEMM: C[m][o] = (s * ws[o]) * sum_k Aq[m][k] * Wq[o][k] ----------------
// m97-verified structure: 128x128 tile, 4 waves (2x2), BK=64 bytes,
// global_load_lds width 16, mfma_i32_16x16x64_i8, 4x4 fragments per wave.
// OUTPUT IS FLOAT32 (harness maps fp16 reference output to float*).
__global__ __launch_bounds__(256) void gemm_i8_kernel(
    const int8_t* __restrict__ Aq,     // [nrt*128][4096] (group-local rows)
    const int8_t* __restrict__ Wq,     // [nct*128][4096] (group-local rows)
    const float* __restrict__ wscale,  // [11008] absolute
    const float* __restrict__ iscale,  // [1]
    float* __restrict__ out,           // [8192][11008] absolute, f32
    int rt0, int ct0, int nct)
{
    __shared__ int8_t As[128 * 64];    // linear: row*64 + kbyte
    __shared__ int8_t Bs[128 * 64];

    const int tid  = threadIdx.x;
    const int lane = tid & 63;
    const int wv   = tid >> 6;
    const int wr   = wv >> 1;          // wave row (0..1)
    const int wc   = wv & 1;           // wave col (0..1)

    const int bn = blockIdx.x % nct;   // local col tile
    const int bm = blockIdx.x / nct;   // local row tile
    const int brow = (rt0 + bm) * 128; // absolute output row base
    const int bcol = (ct0 + bn) * 128; // absolute output col base

    const int8_t* Ab = Aq + (size_t)bm * TILE_BYTES;
    const int8_t* Bb = Wq + (size_t)bn * TILE_BYTES;

    i32x4 acc[4][4] = {};

    const int l15 = lane & 15;
    const int ko  = (lane >> 4) * 16;            // K-quarter byte offset

    for (int kt = 0; kt < IN_F / 64; ++kt) {
        const int k0 = kt * 64;
        __syncthreads();   // previous tile's reads complete before overwrite
        #pragma unroll
        for (int i = 0; i < 2; ++i) {
            const int n   = i * 256 + tid;       // 16B chunk 0..511; wave-uniform base + lane*16 dest
            const int row = n >> 2;
            const int cc  = (n & 3) * 16;
            __builtin_amdgcn_global_load_lds(
                (const __attribute__((address_space(1))) void*)(Ab + (size_t)row * IN_F + k0 + cc),
                (__attribute__((address_space(3))) void*)(As + n * 16), 16, 0, 0);
            __builtin_amdgcn_global_load_lds(
                (const __attribute__((address_space(1))) void*)(Bb + (size_t)row * IN_F + k0 + cc),
                (__attribute__((address_space(3))) void*)(Bs + n * 16), 16, 0, 0);
        }
        __syncthreads();   // compiler drains vmcnt before s_barrier

        i32x4 av[4], bv[4];
        #pragma unroll
        for (int m = 0; m < 4; ++m)
            av[m] = *(const i32x4*)(As + (wr * 64 + m * 16 + l15) * 64 + ko);
        #pragma unroll
        for (int n = 0; n < 4; ++n)
            bv[n] = *(const i32x4*)(Bs + (wc * 64 + n * 16 + l15) * 64 + ko);

        #pragma unroll
        for (int m = 0; m < 4; ++m)
            #pragma unroll
            for (int n = 0; n < 4; ++n)
                acc[m][n] = __builtin_amdgcn_mfma_i32_16x16x64_i8(av[m], bv[n], acc[m][n], 0, 0, 0);
    }

    // epilogue: out = f32(acc * s * ws[col]); C/D map: col=lane&15, row=(lane>>4)*4+j
    const float s = iscale[0];
    #pragma unroll
    for (int n = 0; n < 4; ++n) {
        const int col = bcol + wc * 64 + n * 16 + l15;
        const float sc = s * wscale[col];
        #pragma unroll
        for (int m = 0; m < 4; ++m) {
            const int rbase = brow + wr * 64 + m * 16 + (lane >> 4) * 4;
            #pragma unroll
            for (int j = 0; j < 4; ++j) {
                out[(size_t)(rbase + j) * OUT_F + col] = (float)acc[m][n][j] * sc;
            }
        }
    }
}

// ---------------- Scalar fallback (no workspace), pathological ws only ----------------
__global__ __launch_bounds__(256) void simple_ref_kernel(
    const float* __restrict__ x, const int* __restrict__ w,
    const float* __restrict__ wsc, const float* __restrict__ isc,
    const float* __restrict__ pqs, float* __restrict__ out)
{
    const float s = isc[0];
    const int m = blockIdx.x;
    const int o = blockIdx.y * 256 + threadIdx.x;
    if (o >= OUT_F) return;
    const float wso = wsc[o];
    const float* xr = x + (size_t)m * IN_F;
    const int* wr = w + (size_t)o * IN_F;
    float acc = 0.0f;
    for (int k = 0; k < IN_F; ++k) {
        float xm = __half2float(__float2half(xr[k] * pqs[k]));
        float qf = nearbyintf(xm / s);
        qf = fminf(fmaxf(qf, -128.0f), 127.0f);
        float xdq = __half2float(__float2half(qf * s));
        float wdq = __half2float(__float2half((float)wr[k] * wso));
        acc = fmaf(xdq, wdq, acc);
    }
    out[(size_t)m * OUT_F + o] = acc;
}

extern "C" void kernel_launch(void* const* d_in, const int* in_sizes, int n_in,
                              void* d_out, int out_size, void* d_ws, size_t ws_size,
                              hipStream_t stream)
{
    // Dispatch inputs by element count — immune to ordering assumptions.
    const float* x   = nullptr;   // [8192][4096] f32 (fp16-valued)
    const int*   w   = nullptr;   // [11008][4096] int32
    const float* wsc = nullptr;   // [11008]
    const float* isc = nullptr;   // [1]
    const float* pqs = nullptr;   // [4096] f32 (fp16-valued)
    for (int i = 0; i < n_in; ++i) {
        switch (in_sizes[i]) {
            case MROWS * IN_F:   x   = (const float*)d_in[i]; break; // 33554432
            case OUT_F * IN_F:   w   = (const int*)d_in[i];   break; // 45088768
            case OUT_F:          wsc = (const float*)d_in[i]; break; // 11008
            case 1:              isc = (const float*)d_in[i]; break;
            case IN_F:           pqs = (const float*)d_in[i]; break; // 4096
        }
    }
    float* out = (float*)d_out;   // fp16 reference output -> float32 buffer

    // ---- ws-adaptive group sizing (deterministic: depends only on ws_size) ----
    const size_t total_tiles = (d_ws == nullptr) ? 0 : (ws_size / TILE_BYTES);
    if (total_tiles < 2) {
        dim3 grid(MROWS, (OUT_F + 255) / 256);
        simple_ref_kernel<<<grid, 256, 0, stream>>>(x, w, wsc, isc, pqs, out);
        return;
    }

    int atiles, wtiles;
    if (total_tiles >= RTILES + CTILES) { atiles = RTILES; wtiles = CTILES; }  // 78.6 MB: single shot
    else if (total_tiles >= RTILES + 1) { atiles = RTILES; wtiles = (int)(total_tiles - RTILES); }
    else { atiles = (int)(total_tiles / 2); wtiles = (int)(total_tiles - atiles); }
    if (atiles > RTILES) atiles = RTILES;
    if (wtiles > CTILES) wtiles = CTILES;

    int8_t* Aq = (int8_t*)d_ws;                             // atiles * 512KB
    int8_t* Wq = Aq + (size_t)atiles * TILE_BYTES;          // wtiles * 512KB

    const int n_ag = (RTILES + atiles - 1) / atiles;
    const int n_wg = (CTILES + wtiles - 1) / wtiles;

    if (n_ag == 1) {
        quant_act_kernel<<<RTILES * 256, 256, 0, stream>>>(x, pqs, isc, Aq);
    }
    for (int wg = 0; wg < n_wg; ++wg) {
        const int ct0 = wg * wtiles;
        const int nct = (ct0 + wtiles <= CTILES) ? wtiles : (CTILES - ct0);
        pack_w_kernel<<<nct * 256, 256, 0, stream>>>(w + (size_t)ct0 * 128 * IN_F, Wq);
        for (int ag = 0; ag < n_ag; ++ag) {
            const int rt0 = ag * atiles;
            const int nrt = (rt0 + atiles <= RTILES) ? atiles : (RTILES - rt0);
            if (n_ag > 1) {
                quant_act_kernel<<<nrt * 256, 256, 0, stream>>>(
                    x + (size_t)rt0 * 128 * IN_F, pqs, isc, Aq);
            }
            gemm_i8_kernel<<<nrt * nct, 256, 0, stream>>>(Aq, Wq, wsc, isc, out, rt0, ct0, nct);
        }
    }
}

// Round 9
// 494.711 us; speedup vs baseline: 1.2676x; 1.2676x over previous
//
#include <hip/hip_runtime.h>
#include <hip/hip_fp16.h>
#include <stdint.h>

typedef int i32x4 __attribute__((ext_vector_type(4)));

#define IN_F  4096
#define OUT_F 11008
#define MROWS 8192
#define BM 256
#define BN 256
#define BKB 128                    // K-bytes per tile (i8)
#define NKT (IN_F / BKB)           // 32
#define GRID_M (MROWS / BM)        // 32
#define GRID_N (OUT_F / BN)        // 43
#define NBLK (GRID_M * GRID_N)     // 1376 (divisible by 8 -> simple XCD swizzle)

#define AS1 __attribute__((address_space(1)))
#define AS3 __attribute__((address_space(3)))

// ---------------- Pre-pass 1: smooth + fake-quant activations to int8 ----------------
__global__ __launch_bounds__(256) void quant_act_kernel(
    const float* __restrict__ x, const float* __restrict__ pqs,
    const float* __restrict__ iscale, int8_t* __restrict__ q)
{
    const int i = blockIdx.x * blockDim.x + threadIdx.x;
    const float s = iscale[0];
    const size_t base = (size_t)i * 8;
    const int col = (int)(base & (IN_F - 1));

    const float4 x0 = *(const float4*)(x + base);
    const float4 x1 = *(const float4*)(x + base + 4);
    const float4 p0 = *(const float4*)(pqs + col);
    const float4 p1 = *(const float4*)(pqs + col + 4);

    float xs[8];
    xs[0] = x0.x * p0.x; xs[1] = x0.y * p0.y; xs[2] = x0.z * p0.z; xs[3] = x0.w * p0.w;
    xs[4] = x1.x * p1.x; xs[5] = x1.y * p1.y; xs[6] = x1.z * p1.z; xs[7] = x1.w * p1.w;

    unsigned int lo = 0, hi = 0;
    #pragma unroll
    for (int j = 0; j < 8; ++j) {
        float xm = __half2float(__float2half(xs[j]));   // fp16 Mul materialization
        float qf = nearbyintf(xm / s);                  // f32 div + RNE
        qf = fminf(fmaxf(qf, -128.0f), 127.0f);
        unsigned int b = (unsigned int)((int)qf & 0xff);
        if (j < 4) lo |= b << (8 * j);
        else       hi |= b << (8 * (j - 4));
    }
    *(uint2*)(q + base) = make_uint2(lo, hi);
}

// ---------------- Pre-pass 2: pack int32-stored int8 weights ----------------
__global__ __launch_bounds__(256) void pack_w_kernel(
    const int* __restrict__ w, int8_t* __restrict__ wq)
{
    const size_t i = (size_t)(blockIdx.x * blockDim.x + threadIdx.x) * 8;
    const int4 a = *(const int4*)(w + i);
    const int4 b = *(const int4*)(w + i + 4);
    unsigned int lo = (a.x & 0xff) | ((a.y & 0xff) << 8) | ((a.z & 0xff) << 16) | ((unsigned int)(a.w & 0xff) << 24);
    unsigned int hi = (b.x & 0xff) | ((b.y & 0xff) << 8) | ((b.z & 0xff) << 16) | ((unsigned int)(b.w & 0xff) << 24);
    *(uint2*)(wq + i) = make_uint2(lo, hi);
}

// ---------------- 256x256 i8 GEMM, counted-vmcnt double-buffer, T2 swizzle ----------------
// 8 waves (2M x 4N), per-wave 128x64 output = 8x4 16x16 fragments.
// LDS: 2 buffers x (A 256x128B + B 256x128B) = 128 KiB.
// Swizzle: phys_chunk = chunk ^ (row & 7) within each 128-B row (involution);
// global_load_lds dest is linear, source pre-swizzled, reads swizzled (rule #21).
__global__ __launch_bounds__(512, 2) void gemm_i8_256_kernel(
    const int8_t* __restrict__ Aq,     // [8192][4096]
    const int8_t* __restrict__ Wq,     // [11008][4096]
    const float* __restrict__ wscale,  // [11008]
    const float* __restrict__ iscale,  // [1]
    float* __restrict__ out)           // [8192][11008] f32
{
    __shared__ int8_t lds[131072];
    int8_t* As = lds;                  // [2][256*128]
    int8_t* Bs = lds + 65536;

    const int tid  = threadIdx.x;
    const int lane = tid & 63;
    const int wv   = tid >> 6;         // 0..7
    const int wr   = wv >> 2;          // 0..1  (M half)
    const int wc   = wv & 3;           // 0..3  (N quarter)

    // T1: XCD-aware swizzle (NBLK % 8 == 0 -> bijective)
    const int bid = (int)blockIdx.x;
    const int swz = (bid & 7) * (NBLK / 8) + (bid >> 3);
    const int bm = swz / GRID_N;
    const int bn = swz % GRID_N;
    const int brow = bm * BM, bcol = bn * BN;

    const int8_t* Ab = Aq + (size_t)brow * IN_F;
    const int8_t* Bb = Wq + (size_t)bcol * IN_F;

    // staging: 2048 16B-chunks per operand tile; 4 A + 4 B per thread
    int srow[4], scol[4], sdst[4];
    #pragma unroll
    for (int i = 0; i < 4; ++i) {
        const int n = i * 512 + tid;           // 0..2047
        srow[i] = n >> 3;                      // tile row
        scol[i] = ((n & 7) ^ (srow[i] & 7)) * 16;  // inverse-swizzled source chunk
        sdst[i] = n * 16;                      // linear LDS dest
    }

    i32x4 acc[8][4] = {};

    const int rl = lane & 15;
    const int hk = lane >> 4;                  // K-quarter 0..3
    const int swz0 = ((0 + hk) ^ (rl & 7)) * 16;   // ks=0: chunk hk
    const int swz1 = ((4 + hk) ^ (rl & 7)) * 16;   // ks=1: chunk 4+hk
    const int a_base = (wr * 128 + rl) * 128;  // + mf*2048 + swz
    const int b_base = (wc * 64 + rl) * 128;   // + nf*2048 + swz

    // prologue: stage kt=0 into buf 0
    #pragma unroll
    for (int i = 0; i < 4; ++i) {
        __builtin_amdgcn_global_load_lds((const AS1 void*)(Ab + (size_t)srow[i] * IN_F + scol[i]),
                                         (AS3 void*)(As + sdst[i]), 16, 0, 0);
        __builtin_amdgcn_global_load_lds((const AS1 void*)(Bb + (size_t)srow[i] * IN_F + scol[i]),
                                         (AS3 void*)(Bs + sdst[i]), 16, 0, 0);
    }

    int buf = 0;
    for (int kt = 0; kt < NKT; ++kt) {
        if (kt + 1 < NKT) {
            // issue next tile's 8 loads, then wait for current tile's 8 only
            const int k0 = (kt + 1) * BKB;
            const int off = (buf ^ 1) * 32768;
            #pragma unroll
            for (int i = 0; i < 4; ++i) {
                __builtin_amdgcn_global_load_lds((const AS1 void*)(Ab + (size_t)srow[i] * IN_F + k0 + scol[i]),
                                                 (AS3 void*)(As + off + sdst[i]), 16, 0, 0);
                __builtin_amdgcn_global_load_lds((const AS1 void*)(Bb + (size_t)srow[i] * IN_F + k0 + scol[i]),
                                                 (AS3 void*)(Bs + off + sdst[i]), 16, 0, 0);
            }
            asm volatile("s_waitcnt vmcnt(8)" ::: "memory");   // T4: counted, never 0
        } else {
            asm volatile("s_waitcnt vmcnt(0)" ::: "memory");   // epilogue drain
        }
        __builtin_amdgcn_s_barrier();
        __builtin_amdgcn_sched_barrier(0);

        const int8_t* At = As + buf * 32768;
        const int8_t* Bt = Bs + buf * 32768;

        #pragma unroll
        for (int ks = 0; ks < 2; ++ks) {
            const int csw = ks ? swz1 : swz0;
            i32x4 a[8], b[4];
            #pragma unroll
            for (int mf = 0; mf < 8; ++mf)
                a[mf] = *(const i32x4*)(At + a_base + mf * 2048 + csw);
            #pragma unroll
            for (int nf = 0; nf < 4; ++nf)
                b[nf] = *(const i32x4*)(Bt + b_base + nf * 2048 + csw);
            __builtin_amdgcn_s_setprio(1);                      // T5
            #pragma unroll
            for (int mf = 0; mf < 8; ++mf)
                #pragma unroll
                for (int nf = 0; nf < 4; ++nf)
                    acc[mf][nf] = __builtin_amdgcn_mfma_i32_16x16x64_i8(a[mf], b[nf], acc[mf][nf], 0, 0, 0);
            __builtin_amdgcn_s_setprio(0);
        }
        __builtin_amdgcn_sched_barrier(0);
        __builtin_amdgcn_s_barrier();      // all waves done reading buf before next overwrite
        buf ^= 1;
    }

    // epilogue: out = f32(acc * s * ws[col]); C/D map: col=lane&15, row=hk*4+j
    const float s = iscale[0];
    #pragma unroll
    for (int nf = 0; nf < 4; ++nf) {
        const int col = bcol + wc * 64 + nf * 16 + rl;
        const float sc = s * wscale[col];
        #pragma unroll
        for (int mf = 0; mf < 8; ++mf) {
            const int r0 = brow + wr * 128 + mf * 16 + hk * 4;
            #pragma unroll
            for (int j = 0; j < 4; ++j)
                out[(size_t)(r0 + j) * OUT_F + col] = (float)acc[mf][nf][j] * sc;
        }
    }
}

// ---------------- Scalar fallback (no workspace), pathological ws only ----------------
__global__ __launch_bounds__(256) void simple_ref_kernel(
    const float* __restrict__ x, const int* __restrict__ w,
    const float* __restrict__ wsc, const float* __restrict__ isc,
    const float* __restrict__ pqs, float* __restrict__ out)
{
    const float s = isc[0];
    const int m = blockIdx.x;
    const int o = blockIdx.y * 256 + threadIdx.x;
    if (o >= OUT_F) return;
    const float wso = wsc[o];
    const float* xr = x + (size_t)m * IN_F;
    const int* wr = w + (size_t)o * IN_F;
    float acc = 0.0f;
    for (int k = 0; k < IN_F; ++k) {
        float xm = __half2float(__float2half(xr[k] * pqs[k]));
        float qf = nearbyintf(xm / s);
        qf = fminf(fmaxf(qf, -128.0f), 127.0f);
        float xdq = __half2float(__float2half(qf * s));
        float wdq = __half2float(__float2half((float)wr[k] * wso));
        acc = fmaf(xdq, wdq, acc);
    }
    out[(size_t)m * OUT_F + o] = acc;
}

extern "C" void kernel_launch(void* const* d_in, const int* in_sizes, int n_in,
                              void* d_out, int out_size, void* d_ws, size_t ws_size,
                              hipStream_t stream)
{
    const float* x   = nullptr;
    const int*   w   = nullptr;
    const float* wsc = nullptr;
    const float* isc = nullptr;
    const float* pqs = nullptr;
    for (int i = 0; i < n_in; ++i) {
        switch (in_sizes[i]) {
            case MROWS * IN_F:   x   = (const float*)d_in[i]; break; // 33554432
            case OUT_F * IN_F:   w   = (const int*)d_in[i];   break; // 45088768
            case OUT_F:          wsc = (const float*)d_in[i]; break; // 11008
            case 1:              isc = (const float*)d_in[i]; break;
            case IN_F:           pqs = (const float*)d_in[i]; break; // 4096
        }
    }
    float* out = (float*)d_out;   // fp16 reference output -> float32 buffer

    const size_t need = (size_t)MROWS * IN_F + (size_t)OUT_F * IN_F;  // 78.6 MB
    if (d_ws == nullptr || ws_size < need) {
        dim3 grid(MROWS, (OUT_F + 255) / 256);
        simple_ref_kernel<<<grid, 256, 0, stream>>>(x, w, wsc, isc, pqs, out);
        return;
    }

    int8_t* Aq = (int8_t*)d_ws;
    int8_t* Wq = Aq + (size_t)MROWS * IN_F;

    quant_act_kernel<<<(MROWS * IN_F / 8) / 256, 256, 0, stream>>>(x, pqs, isc, Aq);
    pack_w_kernel<<<(OUT_F * IN_F / 8) / 256, 256, 0, stream>>>(w, Wq);
    gemm_i8_256_kernel<<<NBLK, 512, 0, stream>>>(Aq, Wq, wsc, isc, out);
}